// Round 15
// baseline (118.038 us; speedup 1.0000x reference)
//
#include <hip/hip_runtime.h>

typedef float f4 __attribute__((ext_vector_type(4)));

#define NJ 24
#define BLK 128
#define OUTW 75               // (NJ+1)*3 floats per row
#define RPW 32                // rows per wave (2 lanes cooperate per row)
#define WBUFF (RPW * OUTW)    // 2400 floats = 9.6 KB per wave
#define CPAD 16               // padded const row (floats) -> b128-friendly

__global__ __launch_bounds__(BLK, 4) void fk_main_kernel(
    const float* __restrict__ ang,   // (B, 24)
    const float* __restrict__ xyz,   // (24, 3)
    const float* __restrict__ rpy,   // (24, 3)
    const float* __restrict__ axis,  // (24, 3)
    float* __restrict__ out)         // (B, 75)
{
    // per-wave 9.6 KB region: first hosts the 24x16 const table (floats
    // 0..383), later the 32-row staging buffer (overwrites it after chain).
    __shared__ float buf[(BLK / 64) * WBUFF];

    const int tid = threadIdx.x;
    const int wv = tid >> 6, ln = tid & 63;
    const int half = ln & 1, r = ln >> 1;    // segment (0/1), row-within-wave
    float* wbuf = &buf[wv * WBUFF];

    const long long row = (long long)blockIdx.x * 64 + wv * RPW + r;

    // ---- my segment's 12 angles: 3x f4 (base 48B-> 16B aligned) ----
    const f4* gA = (const f4*)(ang + row * NJ + half * 12);
    f4 A[3];
    A[0] = gA[0]; A[1] = gA[1]; A[2] = gA[2];

    // ---- per-wave consts: lanes 0..23 derive joint ln's 12, 3x b128 write ----
    if (ln < NJ) {
        const int j = ln;
        float rr = rpy[j*3+0] * 0.5f, p = rpy[j*3+1] * 0.5f, yv = rpy[j*3+2] * 0.5f;
        float sr, cr, sp, cp, sy, cy;
        __sincosf(rr, &sr, &cr);
        __sincosf(p,  &sp, &cp);
        __sincosf(yv, &sy, &cy);
        float qw = cr*cp*cy + sr*sp*sy;
        float qx = sr*cp*cy - cr*sp*sy;
        float qy = cr*sp*cy + sr*cp*sy;
        float qz = cr*cp*sy - sr*sp*cy;
        float ax = axis[j*3+0], ay = axis[j*3+1], az = axis[j*3+2];
        float n = sqrtf(ax*ax + ay*ay + az*az);
        float inv = 1.0f / fmaxf(n, 1e-6f);
        float ux = ax*inv, uy = ay*inv, uz = az*inv;
        f4 v0 = { qw, qx, qy, qz };                                   // qA
        f4 v1 = { -(qx*ux + qy*uy + qz*uz),                           // qB
                  qw*ux + qy*uz - qz*uy,
                  qw*uy + qz*ux - qx*uz,
                  qw*uz + qx*uy - qy*ux };
        f4 v2 = { xyz[j*3+0], xyz[j*3+1], xyz[j*3+2], n * 0.5f };     // v, halfnorm
        f4* dst = (f4*)(wbuf + j * CPAD);    // wave-private -> no block barrier
        dst[0] = v0; dst[1] = v1; dst[2] = v2;
    }
    asm volatile("" ::: "memory");   // const-writes -> chain-reads (RAW, same wave)

    // ---- 12-joint segment chain from identity; local positions in regs ----
    float Qw = 1.f, Qx = 0.f, Qy = 0.f, Qz = 0.f;
    float t0 = 0.f, t1 = 0.f, t2 = 0.f;
    float P[36];                              // static indices only -> VGPRs
    #pragma unroll
    for (int i = 0; i < 12; ++i) {
        const f4* cj = (const f4*)(wbuf + (half * 12 + i) * CPAD);  // 2 addrs/wave
        f4 ca = cj[0], cb = cj[1], cv = cj[2];
        float h = A[i >> 2][i & 3] * cv.w;
        float s, cq;
        __sincosf(h, &s, &cq);
        float lw = cq*ca.x + s*cb.x;
        float lx = cq*ca.y + s*cb.y;
        float ly = cq*ca.z + s*cb.z;
        float lz = cq*ca.w + s*cb.w;
        float vx = cv.x, vy = cv.y, vz = cv.z;
        float px = Qy*vz - Qz*vy + Qw*vx;
        float py = Qz*vx - Qx*vz + Qw*vy;
        float pz = Qx*vy - Qy*vx + Qw*vz;
        t0 += vx + 2.f*(Qy*pz - Qz*py);
        t1 += vy + 2.f*(Qz*px - Qx*pz);
        t2 += vz + 2.f*(Qx*py - Qy*px);
        P[3*i+0] = t0; P[3*i+1] = t1; P[3*i+2] = t2;
        float nw = Qw*lw - Qx*lx - Qy*ly - Qz*lz;
        float nx = Qw*lx + Qx*lw + Qy*lz - Qz*ly;
        float ny = Qw*ly - Qx*lz + Qy*lw + Qz*lx;
        float nz = Qw*lz + Qx*ly - Qy*lx + Qz*lw;
        Qw = nw; Qx = nx; Qy = ny; Qz = nz;
    }

    // ---- exchange inclusive transform with pair partner (xor lane 1) ----
    float Jw  = __shfl_xor(Qw, 1);
    float Jx  = __shfl_xor(Qx, 1);
    float Jy  = __shfl_xor(Qy, 1);
    float Jz  = __shfl_xor(Qz, 1);
    float Jt0 = __shfl_xor(t0, 1);
    float Jt1 = __shfl_xor(t1, 1);
    float Jt2 = __shfl_xor(t2, 1);
    // exclusive prefix: identity for segment 0, partner's (seg-0) for segment 1
    Jw  = half ? Jw  : 1.f;
    Jx  = half ? Jx  : 0.f;
    Jy  = half ? Jy  : 0.f;
    Jz  = half ? Jz  : 0.f;
    Jt0 = half ? Jt0 : 0.f;
    Jt1 = half ? Jt1 : 0.f;
    Jt2 = half ? Jt2 : 0.f;

    asm volatile("" ::: "memory");   // last const-read -> stage-writes (WAR)

    // ---- rotate local positions into global frame, stage into row r ----
    // stage banks: addr = 75r + c -> bank (11r + c) mod 32, bijective in r;
    // even/odd column split is a 2-way alias at most (free). No restrict.
    float* ob = wbuf + r * OUTW;
    if (!half) { ob[0] = 0.f; ob[1] = 0.f; ob[2] = 0.f; }
    #pragma unroll
    for (int i = 0; i < 12; ++i) {
        float vx = P[3*i+0], vy = P[3*i+1], vz = P[3*i+2];
        float px = Jy*vz - Jz*vy + Jw*vx;
        float py = Jz*vx - Jx*vz + Jw*vy;
        float pz = Jx*vy - Jy*vx + Jw*vz;
        int c = 3 + half * 36 + 3 * i;
        ob[c+0] = Jt0 + vx + 2.f*(Jy*pz - Jz*py);
        ob[c+1] = Jt1 + vy + 2.f*(Jz*px - Jx*pz);
        ob[c+2] = Jt2 + vz + 2.f*(Jx*py - Jy*px);
    }
    asm volatile("" ::: "memory");   // stage-writes -> dump-reads (RAW order)

    // ---- per-wave coalesced dump: 32 rows x 75 = 600 f4, 9.6 KB contiguous ----
    const f4* lb = (const f4*)wbuf;
    f4* gW = (f4*)(out + ((long long)blockIdx.x * 64 + wv * RPW) * OUTW);
    #pragma unroll
    for (int k = 0; k < 10; ++k) {
        int i = k * 64 + ln;
        if (i < WBUFF / 4) gW[i] = lb[i];
    }
}

extern "C" void kernel_launch(void* const* d_in, const int* in_sizes, int n_in,
                              void* d_out, int out_size, void* d_ws, size_t ws_size,
                              hipStream_t stream) {
    const float* ang  = (const float*)d_in[0];
    const float* xyz  = (const float*)d_in[1];
    const float* rpy  = (const float*)d_in[2];
    const float* axis = (const float*)d_in[3];
    float* out = (float*)d_out;

    const int B = in_sizes[0] / NJ;          // 262144
    const int grid = B / 64;                 // 4096 blocks -> 2 rounds at 16 w/CU
    fk_main_kernel<<<grid, BLK, 0, stream>>>(ang, xyz, rpy, axis, out);
}

// Round 16
// 31.588 us; speedup vs baseline: 3.7368x; 3.7368x over previous
//
#include <hip/hip_runtime.h>

typedef float f4 __attribute__((ext_vector_type(4)));

#define NJ 24
#define BLK 128
#define OUTW 75               // (NJ+1)*3 floats per row
#define RPW 32                // rows per wave (2 lanes cooperate per row)
#define STG (RPW * OUTW)      // 2400 floats staging per wave
#define CFL (NJ * 16)         // 384 floats const table per wave
#define WREG (STG + CFL)      // 2784 floats = 11136 B per wave region

__global__ __launch_bounds__(BLK, 3) void fk_main_kernel(
    const float* __restrict__ ang,   // (B, 24)
    const float* __restrict__ xyz,   // (24, 3)
    const float* __restrict__ rpy,   // (24, 3)
    const float* __restrict__ axis,  // (24, 3)
    float* __restrict__ out)         // (B, 75)
{
    // per-wave region: [0..2399] row staging, [2400..2783] const table
    __shared__ float buf[(BLK / 64) * WREG];   // 22272 B -> 7 blocks/CU, 2.3 rounds

    const int tid = threadIdx.x;
    const int wv = tid >> 6, ln = tid & 63;
    const int half = ln & 1, r = ln >> 1;      // segment (0/1), row-within-wave
    float* wbuf = &buf[wv * WREG];
    float* cst  = wbuf + STG;

    const long long row = (long long)blockIdx.x * 64 + wv * RPW + r;

    // ---- my segment's 12 angles: 3x f4 (byte offset 96*row+48*half, 16B ok) ----
    const f4* gA = (const f4*)(ang + row * NJ + half * 12);
    f4 A0 = gA[0], A1 = gA[1], A2 = gA[2];
    float th[12] = {A0.x,A0.y,A0.z,A0.w, A1.x,A1.y,A1.z,A1.w, A2.x,A2.y,A2.z,A2.w};

    // ---- per-wave consts: lanes 0..23 derive joint ln's 12 floats ----
    if (ln < NJ) {
        const int j = ln;
        float rr = rpy[j*3+0] * 0.5f, p = rpy[j*3+1] * 0.5f, yv = rpy[j*3+2] * 0.5f;
        float sr, cr, sp, cp, sy, cy;
        __sincosf(rr, &sr, &cr);
        __sincosf(p,  &sp, &cp);
        __sincosf(yv, &sy, &cy);
        float qw = cr*cp*cy + sr*sp*sy;
        float qx = sr*cp*cy - cr*sp*sy;
        float qy = cr*sp*cy + sr*cp*sy;
        float qz = cr*cp*sy - sr*sp*cy;
        float ax = axis[j*3+0], ay = axis[j*3+1], az = axis[j*3+2];
        float n = sqrtf(ax*ax + ay*ay + az*az);
        float inv = 1.0f / fmaxf(n, 1e-6f);
        float ux = ax*inv, uy = ay*inv, uz = az*inv;
        f4* dst = (f4*)(cst + j * 16);
        f4 v0 = { qw, qx, qy, qz };                                 // qA
        f4 v1 = { -(qx*ux + qy*uy + qz*uz),                         // qB
                  qw*ux + qy*uz - qz*uy,
                  qw*uy + qz*ux - qx*uz,
                  qw*uz + qx*uy - qy*ux };
        f4 v2 = { xyz[j*3+0], xyz[j*3+1], xyz[j*3+2], n * 0.5f };
        dst[0] = v0; dst[1] = v1; dst[2] = v2;
    }
    asm volatile("" ::: "memory");   // const-writes -> chain-reads (same wave)

    // ---- 12-joint segment chain from identity; positions stream to LDS ----
    // even lane (half=0): prefix=identity -> positions are FINAL, cols 3..38
    // odd  lane (half=1): local positions, cols 39..74, fixed up after exchange
    float* ob = wbuf + r * OUTW;               // banks 11r+c: bijective in r
    float Qw = 1.f, Qx = 0.f, Qy = 0.f, Qz = 0.f;
    float t0 = 0.f, t1 = 0.f, t2 = 0.f;
    const int cbase = 3 + half * 36;

    #pragma unroll
    for (int i = 0; i < 12; ++i) {
        const f4* cj = (const f4*)(cst + (half * 12 + i) * 16);  // 2 addrs/wave
        f4 ca = cj[0], cb = cj[1], cv = cj[2];
        float h = th[i] * cv.w;
        float s, cq;
        __sincosf(h, &s, &cq);
        float lw = cq*ca.x + s*cb.x;
        float lx = cq*ca.y + s*cb.y;
        float ly = cq*ca.z + s*cb.z;
        float lz = cq*ca.w + s*cb.w;
        float vx = cv.x, vy = cv.y, vz = cv.z;
        float px = Qy*vz - Qz*vy + Qw*vx;
        float py = Qz*vx - Qx*vz + Qw*vy;
        float pz = Qx*vy - Qy*vx + Qw*vz;
        t0 += vx + 2.f*(Qy*pz - Qz*py);
        t1 += vy + 2.f*(Qz*px - Qx*pz);
        t2 += vz + 2.f*(Qx*py - Qy*px);
        ob[cbase + 3*i + 0] = t0;
        ob[cbase + 3*i + 1] = t1;
        ob[cbase + 3*i + 2] = t2;
        float nw = Qw*lw - Qx*lx - Qy*ly - Qz*lz;
        float nx = Qw*lx + Qx*lw + Qy*lz - Qz*ly;
        float ny = Qw*ly - Qx*lz + Qy*lw + Qz*lx;
        float nz = Qw*lz + Qx*ly - Qy*lx + Qz*lw;
        Qw = nw; Qx = nx; Qy = ny; Qz = nz;
    }
    if (!half) { ob[0] = 0.f; ob[1] = 0.f; ob[2] = 0.f; }

    // ---- exchange: odd lane gets even partner's final transform ----
    float Jw  = __shfl_xor(Qw, 1);
    float Jx  = __shfl_xor(Qx, 1);
    float Jy  = __shfl_xor(Qy, 1);
    float Jz  = __shfl_xor(Qz, 1);
    float Jt0 = __shfl_xor(t0, 1);
    float Jt1 = __shfl_xor(t1, 1);
    float Jt2 = __shfl_xor(t2, 1);

    // ---- odd-lane fixup in LDS: read local, rotate into global, rewrite ----
    // (same-lane same-address deps; DS in-order per wave; no restrict)
    if (half) {
        #pragma unroll
        for (int i = 0; i < 12; ++i) {
            float vx = ob[39 + 3*i + 0];
            float vy = ob[39 + 3*i + 1];
            float vz = ob[39 + 3*i + 2];
            float px = Jy*vz - Jz*vy + Jw*vx;
            float py = Jz*vx - Jx*vz + Jw*vy;
            float pz = Jx*vy - Jy*vx + Jw*vz;
            ob[39 + 3*i + 0] = Jt0 + vx + 2.f*(Jy*pz - Jz*py);
            ob[39 + 3*i + 1] = Jt1 + vy + 2.f*(Jz*px - Jx*pz);
            ob[39 + 3*i + 2] = Jt2 + vz + 2.f*(Jx*py - Jy*px);
        }
    }
    asm volatile("" ::: "memory");   // stage/fixup-writes -> dump-reads (RAW)

    // ---- per-wave coalesced dump: 32 rows x 75 = 600 f4, 9.6 KB contiguous ----
    const f4* lb = (const f4*)wbuf;
    f4* gW = (f4*)(out + ((long long)blockIdx.x * 64 + wv * RPW) * OUTW);
    #pragma unroll
    for (int k = 0; k < 10; ++k) {
        int i = k * 64 + ln;
        if (i < STG / 4) gW[i] = lb[i];
    }
}

extern "C" void kernel_launch(void* const* d_in, const int* in_sizes, int n_in,
                              void* d_out, int out_size, void* d_ws, size_t ws_size,
                              hipStream_t stream) {
    const float* ang  = (const float*)d_in[0];
    const float* xyz  = (const float*)d_in[1];
    const float* rpy  = (const float*)d_in[2];
    const float* axis = (const float*)d_in[3];
    float* out = (float*)d_out;

    const int B = in_sizes[0] / NJ;          // 262144
    const int grid = B / 64;                 // 4096 blocks -> ~2.3 rounds at 7/CU
    fk_main_kernel<<<grid, BLK, 0, stream>>>(ang, xyz, rpy, axis, out);
}

// Round 17
// 29.204 us; speedup vs baseline: 4.0418x; 1.0816x over previous
//
#include <hip/hip_runtime.h>

typedef float f4 __attribute__((ext_vector_type(4)));

#define NJ 24
#define BLK 64                // single-wave blocks: 16 blocks/CU, fine smear
#define OUTW 75               // (NJ+1)*3 floats per row
#define HROWS 32              // rows staged per dump phase (half wave)
#define HBUF (HROWS * OUTW)   // 2400 floats = 9.6 KB per block (one wave)
#define CPB 2                 // rows per thread: chain1 overlaps dump0 drain

// broadcast lane j's float to all lanes as wave-uniform SGPR (no DS pipe)
#define RL(v, j) __int_as_float(__builtin_amdgcn_readlane(__float_as_int(v), (j)))

__global__ __launch_bounds__(BLK, 4) void fk_main_kernel(
    const float* __restrict__ ang,   // (B, 24)
    const float* __restrict__ xyz,   // (24, 3)
    const float* __restrict__ rpy,   // (24, 3)
    const float* __restrict__ axis,  // (24, 3)
    float* __restrict__ out)         // (B, 75)
{
    __shared__ float wbuf[HBUF];     // 9.6 KB staging bounce (wave-private)

    const int ln = threadIdx.x;      // single wave per block

    // ---- chunk0 angles: 6x f4 (row base 96B -> 16B aligned) ----
    const long long chunk0 = (long long)blockIdx.x * CPB;
    const f4* g0 = (const f4*)(ang + (chunk0 * BLK + ln) * NJ);
    f4 A[6];
    #pragma unroll
    for (int k = 0; k < 6; ++k) A[k] = g0[k];

    // ---- per-joint consts: lanes 0..23 hold joint ln's 12 (chunk-invariant) ----
    float c0=0,c1=0,c2=0,c3=0,c4=0,c5=0,c6=0,c7=0,c8=0,c9=0,c10=0,c11=0;
    if (ln < NJ) {
        const int j = ln;
        float r = rpy[j*3+0] * 0.5f, p = rpy[j*3+1] * 0.5f, yv = rpy[j*3+2] * 0.5f;
        float sr, cr, sp, cp, sy, cy;
        __sincosf(r, &sr, &cr);
        __sincosf(p, &sp, &cp);
        __sincosf(yv, &sy, &cy);
        float qw = cr*cp*cy + sr*sp*sy;
        float qx = sr*cp*cy - cr*sp*sy;
        float qy = cr*sp*cy + sr*cp*sy;
        float qz = cr*cp*sy - sr*sp*cy;
        float ax = axis[j*3+0], ay = axis[j*3+1], az = axis[j*3+2];
        float n = sqrtf(ax*ax + ay*ay + az*az);
        float inv = 1.0f / fmaxf(n, 1e-6f);
        float ux = ax*inv, uy = ay*inv, uz = az*inv;
        c0 = qw; c1 = qx; c2 = qy; c3 = qz;            // qA = qRo
        c4 = -(qx*ux + qy*uy + qz*uz);                  // qB = qRo x (0,u)
        c5 = qw*ux + qy*uz - qz*uy;
        c6 = qw*uy + qz*ux - qx*uz;
        c7 = qw*uz + qx*uy - qy*ux;
        c8 = xyz[j*3+0]; c9 = xyz[j*3+1]; c10 = xyz[j*3+2];
        c11 = n * 0.5f;
    }

    float o[OUTW];                   // compile-time indices only -> VGPRs

    #pragma unroll
    for (int c = 0; c < CPB; ++c) {
        // ---- FK chain for this chunk; consts via readlane, zero DS reads ----
        o[0] = 0.f; o[1] = 0.f; o[2] = 0.f;
        float Qw = 1.f, Qx = 0.f, Qy = 0.f, Qz = 0.f;
        float t0 = 0.f, t1 = 0.f, t2 = 0.f;

        #pragma unroll
        for (int j = 0; j < NJ; ++j) {
            float qa0 = RL(c0, j), qa1 = RL(c1, j), qa2 = RL(c2, j), qa3 = RL(c3, j);
            float qb0 = RL(c4, j), qb1 = RL(c5, j), qb2 = RL(c6, j), qb3 = RL(c7, j);
            float vx  = RL(c8, j), vy  = RL(c9, j), vz  = RL(c10, j);
            float hn  = RL(c11, j);

            float h = A[j >> 2][j & 3] * hn;
            float s, cq;
            __sincosf(h, &s, &cq);
            float lw = cq*qa0 + s*qb0;
            float lx = cq*qa1 + s*qb1;
            float ly = cq*qa2 + s*qb2;
            float lz = cq*qa3 + s*qb3;
            float px = Qy*vz - Qz*vy + Qw*vx;
            float py = Qz*vx - Qx*vz + Qw*vy;
            float pz = Qx*vy - Qy*vx + Qw*vz;
            t0 += vx + 2.f*(Qy*pz - Qz*py);
            t1 += vy + 2.f*(Qz*px - Qx*pz);
            t2 += vz + 2.f*(Qx*py - Qy*px);
            float nw = Qw*lw - Qx*lx - Qy*ly - Qz*lz;
            float nx = Qw*lx + Qx*lw + Qy*lz - Qz*ly;
            float ny = Qw*ly - Qx*lz + Qy*lw + Qz*lx;
            float nz = Qw*lz + Qx*ly - Qy*lx + Qz*lw;
            Qw = nw; Qx = nx; Qy = ny; Qz = nz;
            o[3*(j+1)+0] = t0;
            o[3*(j+1)+1] = t1;
            o[3*(j+1)+2] = t2;
        }

        f4* gW = (f4*)(out + (chunk0 + c) * (BLK * OUTW));

        if (c) {
            asm volatile("" ::: "memory");   // prev dump-reads -> stage-writes (WAR)
        }
        // ---- phase 0: lanes 0..31 stage full rows; wave dumps 9.6/2 KB ----
        // banks (11*ln+k) mod 32 bijective in ln -> conflict-free; no restrict.
        if (ln < HROWS) {
            float* ob = wbuf + ln * OUTW;
            #pragma unroll
            for (int k = 0; k < OUTW; ++k) ob[k] = o[k];
        }
        asm volatile("" ::: "memory");   // stage-writes -> dump-reads (RAW)
        {
            const f4* lb = (const f4*)wbuf;
            #pragma unroll
            for (int k = 0; k < 10; ++k) {
                int i = k * 64 + ln;
                if (i < HBUF / 4) gW[i] = lb[i];
            }
        }
        asm volatile("" ::: "memory");   // dump-reads -> phase-1 stage-writes (WAR)

        // ---- phase 1: lanes 32..63 stage; wave dumps second half ----
        if (ln >= HROWS) {
            float* ob = wbuf + (ln - HROWS) * OUTW;
            #pragma unroll
            for (int k = 0; k < OUTW; ++k) ob[k] = o[k];
        }

        // o[] is dead after stage-1: issue next chunk's angle loads NOW so
        // their latency hides under dump-1 issue + drain (VGPR peak ~100).
        if (c + 1 < CPB) {
            const f4* g1 = (const f4*)(ang + ((chunk0 + 1) * BLK + ln) * NJ);
            #pragma unroll
            for (int k = 0; k < 6; ++k) A[k] = g1[k];
        }

        asm volatile("" ::: "memory");   // stage-writes -> dump-reads (RAW)
        {
            const f4* lb = (const f4*)wbuf;
            #pragma unroll
            for (int k = 0; k < 10; ++k) {
                int i = k * 64 + ln;
                if (i < HBUF / 4) gW[i + HBUF / 4] = lb[i];
            }
        }
        // next chunk's chain is pure VALU -> executes while these stores drain
    }
}

extern "C" void kernel_launch(void* const* d_in, const int* in_sizes, int n_in,
                              void* d_out, int out_size, void* d_ws, size_t ws_size,
                              hipStream_t stream) {
    const float* ang  = (const float*)d_in[0];
    const float* xyz  = (const float*)d_in[1];
    const float* rpy  = (const float*)d_in[2];
    const float* axis = (const float*)d_in[3];
    float* out = (float*)d_out;

    const int B = in_sizes[0] / NJ;              // 262144
    const int grid = B / (BLK * CPB);            // 2048 blocks -> 16/CU, one round
    fk_main_kernel<<<grid, BLK, 0, stream>>>(ang, xyz, rpy, axis, out);
}

// Round 18
// 24.810 us; speedup vs baseline: 4.7577x; 1.1771x over previous
//
#include <hip/hip_runtime.h>

typedef float f4 __attribute__((ext_vector_type(4)));
typedef float f2 __attribute__((ext_vector_type(2)));

#define NJ 24
#define BLK 128
#define OUTW 75               // (NJ+1)*3 floats per row
#define HROWS 32              // rows staged per dump phase (half wave)
#define HBUF (HROWS * OUTW)   // 2400 floats = 9.6 KB per wave

// broadcast lane j's float to all lanes as wave-uniform SGPR (no DS pipe)
#define RL(v, j) __int_as_float(__builtin_amdgcn_readlane(__float_as_int(v), (j)))

__global__ __launch_bounds__(BLK, 4) void fk_main_kernel(
    const float* __restrict__ ang,   // (B, 24)
    const float* __restrict__ xyz,   // (24, 3)
    const float* __restrict__ rpy,   // (24, 3)
    const float* __restrict__ axis,  // (24, 3)
    float* __restrict__ out)         // (B, 75)
{
    // LDS is ONLY the per-wave staging bounce: 2 x 9.6 KB = 19200 B/block
    __shared__ float buf[(BLK / 64) * HBUF];

    const int tid = threadIdx.x;
    const int wv = tid >> 6, ln = tid & 63;
    float* wbuf = &buf[wv * HBUF];

    // ---- my row's 24 angles via 6x float4 (row base 96B -> 16B aligned) ----
    const long long row = (long long)blockIdx.x * BLK + tid;
    const f4* gA = (const f4*)(ang + row * NJ);
    f4 A[6];
    #pragma unroll
    for (int k = 0; k < 6; ++k) A[k] = gA[k];

    // ---- per-joint consts: lanes 0..23 of EACH wave hold joint ln's 12 ----
    float c0=0,c1=0,c2=0,c3=0,c4=0,c5=0,c6=0,c7=0,c8=0,c9=0,c10=0,c11=0;
    if (ln < NJ) {
        const int j = ln;
        float r = rpy[j*3+0] * 0.5f, p = rpy[j*3+1] * 0.5f, yv = rpy[j*3+2] * 0.5f;
        float sr, cr, sp, cp, sy, cy;
        __sincosf(r, &sr, &cr);
        __sincosf(p, &sp, &cp);
        __sincosf(yv, &sy, &cy);
        float qw = cr*cp*cy + sr*sp*sy;
        float qx = sr*cp*cy - cr*sp*sy;
        float qy = cr*sp*cy + sr*cp*sy;
        float qz = cr*cp*sy - sr*sp*cy;
        float ax = axis[j*3+0], ay = axis[j*3+1], az = axis[j*3+2];
        float n = sqrtf(ax*ax + ay*ay + az*az);
        float inv = 1.0f / fmaxf(n, 1e-6f);
        float ux = ax*inv, uy = ay*inv, uz = az*inv;
        c0 = qw; c1 = qx; c2 = qy; c3 = qz;            // qA = qRo
        c4 = -(qx*ux + qy*uy + qz*uz);                  // qB = qRo x (0,u)
        c5 = qw*ux + qy*uz - qz*uy;
        c6 = qw*uy + qz*ux - qx*uz;
        c7 = qw*uz + qx*uy - qy*ux;
        c8 = xyz[j*3+0]; c9 = xyz[j*3+1]; c10 = xyz[j*3+2];
        c11 = n * 0.5f;
    }

    // ---- single FK chain; consts via readlane; math in f2 pairs so the
    //      backend emits v_pk_{mul,fma}_f32 (VOP3P, 2 FMA/slot, neg mods) ----
    float o[OUTW];                       // all indices compile-time -> VGPRs
    o[0] = 0.f; o[1] = 0.f; o[2] = 0.f;
    float Qw = 1.f, Qx = 0.f, Qy = 0.f, Qz = 0.f;
    f2 T01 = {0.f, 0.f};                 // (t0, t1)
    float t2 = 0.f;

    #pragma unroll
    for (int j = 0; j < NJ; ++j) {
        float qa0 = RL(c0, j), qa1 = RL(c1, j), qa2 = RL(c2, j), qa3 = RL(c3, j);
        float qb0 = RL(c4, j), qb1 = RL(c5, j), qb2 = RL(c6, j), qb3 = RL(c7, j);
        float vx  = RL(c8, j), vy  = RL(c9, j), vz  = RL(c10, j);
        float hn  = RL(c11, j);

        float h = A[j >> 2][j & 3] * hn;
        float s, cq;
        __sincosf(h, &s, &cq);

        // local quat: 2 pk_mul + 2 pk_fma
        f2 Lwx = cq * f2{qa0, qa1} + s * f2{qb0, qb1};
        f2 Lyz = cq * f2{qa2, qa3} + s * f2{qb2, qb3};
        float lw = Lwx.x, lx = Lwx.y, ly = Lyz.x, lz = Lyz.y;

        // rotate v by parent Q, accumulate t (pairs + scalar lane)
        f2 Qyz = {Qy, Qz}, Qzx = {Qz, Qx};
        f2 u01 = Qyz * f2{vz, vx} - Qzx * f2{vy, vz} + Qw * f2{vx, vy};
        float u2 = Qx*vy - Qy*vx + Qw*vz;
        f2 w01 = Qyz * f2{u2, u01.x} - Qzx * f2{u01.y, u2};
        float w2 = Qx*u01.y - Qy*u01.x;
        T01 = T01 + f2{vx, vy} + 2.f * w01;
        t2  = t2 + vz + 2.f * w2;
        o[3*(j+1)+0] = T01.x;
        o[3*(j+1)+1] = T01.y;
        o[3*(j+1)+2] = t2;

        // Q = Q (x) q_loc : 2x (pk_mul + 3 pk_fma), negs fold into VOP3P mods
        f2 Nwx = Qw * Lwx + Qx * f2{-lx, lw} + Qy * f2{-ly, lz} + Qz * f2{-lz, -ly};
        f2 Nyz = Qw * Lyz + Qx * f2{-lz, ly} + Qy * f2{lw, -lx} + Qz * f2{lx, lw};
        Qw = Nwx.x; Qx = Nwx.y; Qy = Nyz.x; Qz = Nyz.y;
    }

    // global f4 base for this wave's 64 rows (64*75*4 = 19200 B contiguous)
    f4* gW = (f4*)(out + ((long long)blockIdx.x * BLK + wv * 64) * OUTW);

    // ---- phase 0: lanes 0..31 stage full rows; whole wave dumps 9.6 KB ----
    // staging addr = ln*75 + k -> bank (11*ln + k) mod 32: bijective in ln
    // -> conflict-free. LDS ptrs deliberately NOT restrict (they alias).
    if (ln < HROWS) {
        float* ob = wbuf + ln * OUTW;
        #pragma unroll
        for (int k = 0; k < OUTW; ++k) ob[k] = o[k];
    }
    asm volatile("" ::: "memory");   // stage-writes -> dump-reads (RAW order)
    {
        const f4* lb = (const f4*)wbuf;          // 600 f4, contiguous
        #pragma unroll
        for (int k = 0; k < 10; ++k) {
            int i = k * 64 + ln;
            if (i < HBUF / 4) gW[i] = lb[i];
        }
    }
    asm volatile("" ::: "memory");   // dump-reads -> phase-1 stage-writes (WAR)

    // ---- phase 1: lanes 32..63 stage; whole wave dumps second 9.6 KB ----
    if (ln >= HROWS) {
        float* ob = wbuf + (ln - HROWS) * OUTW;
        #pragma unroll
        for (int k = 0; k < OUTW; ++k) ob[k] = o[k];
    }
    asm volatile("" ::: "memory");   // stage-writes -> dump-reads (RAW order)
    {
        const f4* lb = (const f4*)wbuf;
        #pragma unroll
        for (int k = 0; k < 10; ++k) {
            int i = k * 64 + ln;
            if (i < HBUF / 4) gW[i + HBUF / 4] = lb[i];
        }
    }
}

extern "C" void kernel_launch(void* const* d_in, const int* in_sizes, int n_in,
                              void* d_out, int out_size, void* d_ws, size_t ws_size,
                              hipStream_t stream) {
    const float* ang  = (const float*)d_in[0];
    const float* xyz  = (const float*)d_in[1];
    const float* rpy  = (const float*)d_in[2];
    const float* axis = (const float*)d_in[3];
    float* out = (float*)d_out;

    const int B = in_sizes[0] / NJ;          // 262144
    const int grid = B / BLK;                // 2048 = 8 blocks/CU, one round
    fk_main_kernel<<<grid, BLK, 0, stream>>>(ang, xyz, rpy, axis, out);
}